// Round 1
// baseline (827.910 us; speedup 1.0000x reference)
//
#include <hip/hip_runtime.h>
#include <hip/hip_bf16.h>
#include <math.h>

typedef __attribute__((ext_vector_type(8))) short bf16x8;
typedef __attribute__((ext_vector_type(4))) float f32x4;

#define DEVI __device__ __forceinline__

constexpr int B_ = 4, T_ = 1024, C_ = 1024, H_ = 16, HD_ = 64, DI_ = 128;
constexpr int NTOK = B_ * T_;      // 4096
constexpr int C4 = 4 * C_;         // 4096
constexpr float LAMBDA_CONF = 0.1f;

DEVI short f2bf(float f) {
  unsigned u = __builtin_bit_cast(unsigned, f);
  u += 0x7fffu + ((u >> 16) & 1u);   // RNE
  return (short)(u >> 16);
}
DEVI unsigned pk2(float a, float b) {
  return (unsigned)(unsigned short)f2bf(a) | ((unsigned)(unsigned short)f2bf(b) << 16);
}
DEVI float sigm(float x) { return 1.f / (1.f + __expf(-x)); }
DEVI float geluf(float x) { return 0.5f * x * (1.f + erff(x * 0.70710678118654752440f)); }

// ---------------- weight transpose + f32->bf16 convert: W[K][N] -> Wt[N][K] ----------------
__global__ __launch_bounds__(256) void transpose_cvt(const float* __restrict__ W,
                                                     short* __restrict__ Wt, int K, int N) {
  __shared__ float s[32][33];
  int n0 = blockIdx.x * 32, k0 = blockIdx.y * 32;
  int tx = threadIdx.x & 31, ty = threadIdx.x >> 5;  // ty 0..7
#pragma unroll
  for (int i = 0; i < 4; i++)
    s[ty + i * 8][tx] = W[(size_t)(k0 + ty + i * 8) * N + n0 + tx];
  __syncthreads();
#pragma unroll
  for (int i = 0; i < 4; i++)
    Wt[(size_t)(n0 + ty + i * 8) * K + k0 + tx] = f2bf(s[tx][ty + i * 8]);
}

// ---------------- block reduce helper (256 threads) ----------------
DEVI float blk_red(float v, volatile float* sm) {
  int lane = threadIdx.x & 63, wv = threadIdx.x >> 6;
#pragma unroll
  for (int o = 32; o; o >>= 1) v += __shfl_down(v, o);
  __syncthreads();
  if (lane == 0) sm[wv] = v;
  __syncthreads();
  return sm[0] + sm[1] + sm[2] + sm[3];
}

// ---------------- LayerNorm (+ optional per-token gate computations) ----------------
template <int FULL>
__global__ __launch_bounds__(256) void ln_kernel(
    const float* __restrict__ X, const float* __restrict__ lnw, const float* __restrict__ lnb,
    float* __restrict__ Out,
    const float* __restrict__ gw, const float* __restrict__ gb,
    const float* __restrict__ mw, const float* __restrict__ mb,
    const float* __restrict__ ew, const float* __restrict__ eb,
    float* __restrict__ gammaA, float* __restrict__ epsA, float* __restrict__ massA,
    float* __restrict__ coefA, float* __restrict__ hmagA) {
  __shared__ float sm[4];
  int tok = blockIdx.x;
  const float* x = X + (size_t)tok * C_;
  int t4 = threadIdx.x * 4;
  float4 xv = *(const float4*)&x[t4];
  float s = xv.x + xv.y + xv.z + xv.w;
  float ss = xv.x * xv.x + xv.y * xv.y + xv.z * xv.z + xv.w * xv.w;
  s = blk_red(s, sm);
  ss = blk_red(ss, sm);
  float mu = s * (1.f / C_);
  float var = ss * (1.f / C_) - mu * mu;
  float rs = rsqrtf(var + 1e-5f);
  float4 wv = *(const float4*)&lnw[t4];
  float4 bv = *(const float4*)&lnb[t4];
  float4 hn;
  hn.x = (xv.x - mu) * rs * wv.x + bv.x;
  hn.y = (xv.y - mu) * rs * wv.y + bv.y;
  hn.z = (xv.z - mu) * rs * wv.z + bv.z;
  hn.w = (xv.w - mu) * rs * wv.w + bv.w;
  *(float4*)&Out[(size_t)tok * C_ + t4] = hn;
  if (FULL) {
    float4 gwv = *(const float4*)&gw[t4];
    float4 mwv = *(const float4*)&mw[t4];
    float4 ewv = *(const float4*)&ew[t4];
    float gd = hn.x * gwv.x + hn.y * gwv.y + hn.z * gwv.z + hn.w * gwv.w;
    float md = xv.x * mwv.x + xv.y * mwv.y + xv.z * mwv.z + xv.w * mwv.w;
    float ed = xv.x * ewv.x + xv.y * ewv.y + xv.z * ewv.z + xv.w * ewv.w;
    float h2 = hn.x * hn.x + hn.y * hn.y + hn.z * hn.z + hn.w * hn.w;
    gd = blk_red(gd, sm);
    md = blk_red(md, sm);
    ed = blk_red(ed, sm);
    h2 = blk_red(h2, sm);
    if (threadIdx.x == 0) {
      float g = sigm(gd + gb[0]);
      float xm = md + mb[0];
      float sp = (xm > 20.f) ? xm : log1pf(expf(xm));
      float msv = 1.f + sp;
      float epv = sigm(ed + eb[0]);
      gammaA[tok] = g;
      massA[tok] = msv;
      epsA[tok] = epv;
      coefA[tok] = epv / msv;
      hmagA[tok] = sqrtf(h2);
    }
  }
}

// ---------------- generic bf16 MFMA GEMM: C[M,N] = A[M,K] * Bt[N,K]^T (+epilogue) ----------------
// EPI: 0 f32 store, 1 bf16 store, 2 wo (bias - lambda*resid), 3 velocity (resid + tok*acc),
//      4 bias+gelu -> bf16, 5 lg2 (resid + sigmoid(tok-1)*(acc+bias)), 6 mlp2 (resid+acc+bias)
template <int ABF, int EPI>
__global__ __launch_bounds__(256) void gemm_bt(
    const void* __restrict__ Ap, const short* __restrict__ Bt, void* __restrict__ Outp,
    const float* __restrict__ bias, const float* __restrict__ resid,
    const float* __restrict__ tokv, int M, int N, int K) {
  __shared__ short As[128][40];
  __shared__ short Bs[128][40];
  int tid = threadIdx.x, lane = tid & 63, w = tid >> 6;
  int wr = w >> 1, wc = w & 1;
  int fr = lane & 15, fg = lane >> 4;
  int nT = N >> 7;
  int bm = (blockIdx.x / nT) << 7;
  int bn = (blockIdx.x % nT) << 7;
  f32x4 acc[4][4] = {};
  int sr = tid >> 1;
  int sc = (tid & 1) << 4;

  for (int kt = 0; kt < K; kt += 32) {
    if (ABF) {
      const short* A = (const short*)Ap;
      const short* p = A + (size_t)(bm + sr) * K + kt + sc;
      *(uint4*)&As[sr][sc] = *(const uint4*)p;
      *(uint4*)&As[sr][sc + 8] = *(const uint4*)(p + 8);
    } else {
      const float* A = (const float*)Ap;
      const float* p = A + (size_t)(bm + sr) * K + kt + sc;
      float4 f0 = *(const float4*)p;
      float4 f1 = *(const float4*)(p + 4);
      float4 f2 = *(const float4*)(p + 8);
      float4 f3 = *(const float4*)(p + 12);
      uint4 w0, w1;
      w0.x = pk2(f0.x, f0.y); w0.y = pk2(f0.z, f0.w);
      w0.z = pk2(f1.x, f1.y); w0.w = pk2(f1.z, f1.w);
      w1.x = pk2(f2.x, f2.y); w1.y = pk2(f2.z, f2.w);
      w1.z = pk2(f3.x, f3.y); w1.w = pk2(f3.z, f3.w);
      *(uint4*)&As[sr][sc] = w0;
      *(uint4*)&As[sr][sc + 8] = w1;
    }
    {
      const short* p = Bt + (size_t)(bn + sr) * K + kt + sc;
      *(uint4*)&Bs[sr][sc] = *(const uint4*)p;
      *(uint4*)&Bs[sr][sc + 8] = *(const uint4*)(p + 8);
    }
    __syncthreads();
    bf16x8 af[4], bfr[4];
#pragma unroll
    for (int i = 0; i < 4; i++) af[i] = *(const bf16x8*)&As[wr * 64 + i * 16 + fr][fg * 8];
#pragma unroll
    for (int i = 0; i < 4; i++) bfr[i] = *(const bf16x8*)&Bs[wc * 64 + i * 16 + fr][fg * 8];
#pragma unroll
    for (int mi = 0; mi < 4; mi++)
#pragma unroll
      for (int ni = 0; ni < 4; ni++)
        acc[mi][ni] = __builtin_amdgcn_mfma_f32_16x16x32_bf16(af[mi], bfr[ni], acc[mi][ni], 0, 0, 0);
    __syncthreads();
  }

#pragma unroll
  for (int mi = 0; mi < 4; mi++) {
    int row0 = bm + wr * 64 + mi * 16 + fg * 4;
#pragma unroll
    for (int ni = 0; ni < 4; ni++) {
      int col = bn + wc * 64 + ni * 16 + fr;
#pragma unroll
      for (int r = 0; r < 4; r++) {
        int row = row0 + r;
        size_t idx = (size_t)row * N + col;
        float v = acc[mi][ni][r];
        if (EPI == 0) {
          ((float*)Outp)[idx] = v;
        } else if (EPI == 1) {
          ((short*)Outp)[idx] = f2bf(v);
        } else if (EPI == 2) {
          ((float*)Outp)[idx] = v + bias[col] - LAMBDA_CONF * resid[idx];
        } else if (EPI == 3) {
          ((float*)Outp)[idx] = resid[idx] + tokv[row] * v;
        } else if (EPI == 4) {
          float x = v + bias[col];
          ((short*)Outp)[idx] = f2bf(geluf(x));
        } else if (EPI == 5) {
          float x = v + bias[col];
          float g = sigm(tokv[row] - 1.f);
          ((float*)Outp)[idx] = resid[idx] + g * x;
        } else if (EPI == 6) {
          ((float*)Outp)[idx] = resid[idx] + v + bias[col];
        }
      }
    }
  }
}

// ---------------- flash attention (full, non-causal), bf16 MFMA ----------------
// grid: (T/64, B*H); block 256 (4 waves, 16 q-rows each)
__global__ __launch_bounds__(256) void attn_kernel(const short* __restrict__ Q,
                                                   const short* __restrict__ K,
                                                   const short* __restrict__ V,
                                                   float* __restrict__ Fout) {
  __shared__ short Ks[32][72];
  __shared__ short Vs[64][40];
  __shared__ short Ps[4][16][32];
  int bh = blockIdx.y;
  int b = bh >> 4, h = bh & 15;
  int qt0 = blockIdx.x * 64;
  int tid = threadIdx.x, lane = tid & 63, w = tid >> 6;
  int fr = lane & 15, fg = lane >> 4;

  size_t base = ((size_t)b * T_) * C_ + h * 64;
  int qrow = qt0 + w * 16 + fr;
  bf16x8 qf0 = *(const bf16x8*)&Q[base + (size_t)qrow * C_ + fg * 8];
  bf16x8 qf1 = *(const bf16x8*)&Q[base + (size_t)qrow * C_ + 32 + fg * 8];

  f32x4 oacc[4] = {};
  float m_run = -1e30f, l_run = 0.f;

  int srow = tid >> 3;
  int scol = (tid & 7) * 8;

  for (int kt = 0; kt < T_; kt += 32) {
    *(uint4*)&Ks[srow][scol] = *(const uint4*)&K[base + (size_t)(kt + srow) * C_ + scol];
    {
      uint4 vv = *(const uint4*)&V[base + (size_t)(kt + srow) * C_ + scol];
      const short* sp = (const short*)&vv;
#pragma unroll
      for (int i = 0; i < 8; i++) Vs[scol + i][srow] = sp[i];
    }
    __syncthreads();

    // S^T = K * Q^T  (rows = keys, cols = q-rows)
    f32x4 sacc[2];
#pragma unroll
    for (int kb = 0; kb < 2; kb++) {
      f32x4 z = {};
      bf16x8 kf0 = *(const bf16x8*)&Ks[kb * 16 + fr][fg * 8];
      bf16x8 kf1 = *(const bf16x8*)&Ks[kb * 16 + fr][32 + fg * 8];
      z = __builtin_amdgcn_mfma_f32_16x16x32_bf16(kf0, qf0, z, 0, 0, 0);
      z = __builtin_amdgcn_mfma_f32_16x16x32_bf16(kf1, qf1, z, 0, 0, 0);
      sacc[kb] = z;
    }
    float mt = -1e30f;
#pragma unroll
    for (int kb = 0; kb < 2; kb++)
#pragma unroll
      for (int r = 0; r < 4; r++) {
        sacc[kb][r] *= 0.125f;  // 1/sqrt(64)/TAU
        mt = fmaxf(mt, sacc[kb][r]);
      }
    mt = fmaxf(mt, __shfl_xor(mt, 16));
    mt = fmaxf(mt, __shfl_xor(mt, 32));
    float m_new = fmaxf(m_run, mt);
    float alpha = __expf(m_run - m_new);
    float psum = 0.f;
    float pv[8];
#pragma unroll
    for (int kb = 0; kb < 2; kb++)
#pragma unroll
      for (int r = 0; r < 4; r++) {
        float p = __expf(sacc[kb][r] - m_new);
        pv[kb * 4 + r] = p;
        psum += p;
      }
    psum += __shfl_xor(psum, 16);
    psum += __shfl_xor(psum, 32);
    l_run = l_run * alpha + psum;
    m_run = m_new;

    // write P (bf16) to wave-private LDS: Ps[w][qcol=fr][key]
    {
      uint2 p0, p1;
      p0.x = pk2(pv[0], pv[1]); p0.y = pk2(pv[2], pv[3]);
      p1.x = pk2(pv[4], pv[5]); p1.y = pk2(pv[6], pv[7]);
      *(uint2*)&Ps[w][fr][fg * 4] = p0;
      *(uint2*)&Ps[w][fr][16 + fg * 4] = p1;
    }
    // rescale O by alpha (per O-row = fg*4+r)
    float ar[4];
#pragma unroll
    for (int r = 0; r < 4; r++) ar[r] = __shfl(alpha, fg * 4 + r);
#pragma unroll
    for (int ni = 0; ni < 4; ni++)
#pragma unroll
      for (int r = 0; r < 4; r++) oacc[ni][r] *= ar[r];

    asm volatile("s_waitcnt lgkmcnt(0)" ::: "memory");
    bf16x8 pa = *(const bf16x8*)&Ps[w][fr][fg * 8];
#pragma unroll
    for (int ni = 0; ni < 4; ni++) {
      bf16x8 vf = *(const bf16x8*)&Vs[ni * 16 + fr][fg * 8];
      oacc[ni] = __builtin_amdgcn_mfma_f32_16x16x32_bf16(pa, vf, oacc[ni], 0, 0, 0);
    }
    __syncthreads();
  }

  float lr[4];
#pragma unroll
  for (int r = 0; r < 4; r++) lr[r] = __shfl(l_run, fg * 4 + r);
#pragma unroll
  for (int ni = 0; ni < 4; ni++)
#pragma unroll
    for (int r = 0; r < 4; r++) {
      int tok = b * T_ + qt0 + w * 16 + fg * 4 + r;
      Fout[(size_t)tok * C_ + h * 64 + ni * 16 + fr] = oacc[ni][r] / lr[r];
    }
}

// ---------------- sequential momentum scan: m_t = g_t*m + c_t*f_t ----------------
__global__ __launch_bounds__(128) void scan_kernel(const float* __restrict__ f_proj,
                                                   const float* __restrict__ gam,
                                                   const float* __restrict__ coef,
                                                   float* __restrict__ m_out) {
  int b = blockIdx.x;
  int d = threadIdx.x;
  const float* fp = f_proj + (size_t)b * T_ * DI_ + d;
  const float* g = gam + (size_t)b * T_;
  const float* c = coef + (size_t)b * T_;
  float* mo = m_out + (size_t)b * T_ * DI_ + d;
  float m = 0.f;
  for (int t = 0; t < T_; t += 8) {
    float fv[8], gv[8], cv[8];
#pragma unroll
    for (int i = 0; i < 8; i++) {
      fv[i] = fp[(size_t)(t + i) * DI_];
      gv[i] = g[t + i];
      cv[i] = c[t + i];
    }
#pragma unroll
    for (int i = 0; i < 8; i++) {
      m = gv[i] * m + cv[i] * fv[i];
      mo[(size_t)(t + i) * DI_] = m;
    }
  }
}

// ---------------- fsi ----------------
__global__ __launch_bounds__(256) void fsi_kernel(const float* __restrict__ f_proj,
                                                  const float* __restrict__ hmag,
                                                  float* __restrict__ fsi_out) {
  int tok = blockIdx.x * 4 + (threadIdx.x >> 6);
  int l = threadIdx.x & 63;
  float2 v = *(const float2*)&f_proj[(size_t)tok * DI_ + l * 2];
  float s = v.x * v.x + v.y * v.y;
#pragma unroll
  for (int o = 32; o; o >>= 1) s += __shfl_down(s, o);
  if (l == 0) fsi_out[tok] = hmag[tok] / (2.f * sqrtf(s) + 1e-6f);
}

// ---------------- launcher ----------------
extern "C" void kernel_launch(void* const* d_in, const int* in_sizes, int n_in,
                              void* d_out, int out_size, void* d_ws, size_t ws_size,
                              hipStream_t stream) {
  (void)in_sizes; (void)n_in; (void)out_size; (void)ws_size;
  const float* h = (const float*)d_in[0];
  const float* ln_w = (const float*)d_in[1];
  const float* ln_b = (const float*)d_in[2];
  const float* w_q = (const float*)d_in[3];
  const float* w_k = (const float*)d_in[4];
  const float* w_v = (const float*)d_in[5];
  const float* w_o = (const float*)d_in[6];
  const float* b_o = (const float*)d_in[7];
  const float* U = (const float*)d_in[8];
  const float* V = (const float*)d_in[9];
  const float* gamma_w = (const float*)d_in[10];
  const float* gamma_b = (const float*)d_in[11];
  const float* mass_w = (const float*)d_in[12];
  const float* mass_b = (const float*)d_in[13];
  const float* eps_w = (const float*)d_in[14];
  const float* eps_b = (const float*)d_in[15];
  const float* lg_w1 = (const float*)d_in[16];
  const float* lg_b1 = (const float*)d_in[17];
  const float* lg_w2 = (const float*)d_in[18];
  const float* lg_b2 = (const float*)d_in[19];
  const float* mlp_w1 = (const float*)d_in[20];
  const float* mlp_b1 = (const float*)d_in[21];
  const float* mlp_w2 = (const float*)d_in[22];
  const float* mlp_b2 = (const float*)d_in[23];

  float* out_h = (float*)d_out;
  float* out_m = out_h + (size_t)NTOK * C_;
  float* out_fsi = out_m + (size_t)NTOK * DI_;

  char* wsb = (char*)d_ws;
  size_t off = 0;
  auto al = [&](size_t bytes) {
    void* p = wsb + off;
    off += (bytes + 255) & ~(size_t)255;
    return p;
  };
  short* wqt = (short*)al((size_t)C_ * C_ * 2);
  short* wkt = (short*)al((size_t)C_ * C_ * 2);
  short* wvt = (short*)al((size_t)C_ * C_ * 2);
  short* wot = (short*)al((size_t)C_ * C_ * 2);
  short* ut = (short*)al((size_t)DI_ * C_ * 2);
  short* vt = (short*)al((size_t)C_ * DI_ * 2);
  short* lg1t = (short*)al((size_t)C4 * C_ * 2);
  short* lg2t = (short*)al((size_t)C_ * C4 * 2);
  short* mlp1t = (short*)al((size_t)C4 * C_ * 2);
  short* mlp2t = (short*)al((size_t)C_ * C4 * 2);
  float* h_norm = (float*)al((size_t)NTOK * C_ * 4);       // also f_total (in-place)
  short* qkv = (short*)al((size_t)3 * NTOK * C_ * 2);
  short* qb = qkv;
  short* kb = qkv + (size_t)NTOK * C_;
  short* vb = qkv + (size_t)2 * NTOK * C_;
  float* fbuf = (float*)al((size_t)NTOK * C_ * 4);         // force, then hn2/hn3
  float* f_proj = (float*)al((size_t)NTOK * DI_ * 4);
  short* act = (short*)al((size_t)NTOK * C4 * 2);
  float* h_pre = (float*)al((size_t)NTOK * C_ * 4);
  float* gammaA = (float*)al((size_t)NTOK * 4);
  float* epsA = (float*)al((size_t)NTOK * 4);
  float* massA = (float*)al((size_t)NTOK * 4);
  float* coefA = (float*)al((size_t)NTOK * 4);
  float* hmagA = (float*)al((size_t)NTOK * 4);
  float* h_new = (float*)qkv;  // overlays q+k region (free after attention)

  dim3 blk(256);
  // weight prep
  transpose_cvt<<<dim3(C_ / 32, C_ / 32), blk, 0, stream>>>(w_q, wqt, C_, C_);
  transpose_cvt<<<dim3(C_ / 32, C_ / 32), blk, 0, stream>>>(w_k, wkt, C_, C_);
  transpose_cvt<<<dim3(C_ / 32, C_ / 32), blk, 0, stream>>>(w_v, wvt, C_, C_);
  transpose_cvt<<<dim3(C_ / 32, C_ / 32), blk, 0, stream>>>(w_o, wot, C_, C_);
  transpose_cvt<<<dim3(DI_ / 32, C_ / 32), blk, 0, stream>>>(U, ut, C_, DI_);
  transpose_cvt<<<dim3(C_ / 32, DI_ / 32), blk, 0, stream>>>(V, vt, DI_, C_);
  transpose_cvt<<<dim3(C4 / 32, C_ / 32), blk, 0, stream>>>(lg_w1, lg1t, C_, C4);
  transpose_cvt<<<dim3(C_ / 32, C4 / 32), blk, 0, stream>>>(lg_w2, lg2t, C4, C_);
  transpose_cvt<<<dim3(C4 / 32, C_ / 32), blk, 0, stream>>>(mlp_w1, mlp1t, C_, C4);
  transpose_cvt<<<dim3(C_ / 32, C4 / 32), blk, 0, stream>>>(mlp_w2, mlp2t, C4, C_);

  // LN1 + gates
  ln_kernel<1><<<NTOK, blk, 0, stream>>>(h, ln_w, ln_b, h_norm, gamma_w, gamma_b, mass_w,
                                         mass_b, eps_w, eps_b, gammaA, epsA, massA, coefA,
                                         hmagA);
  // QKV
  int gQ = (NTOK / 128) * (C_ / 128);
  gemm_bt<0, 1><<<gQ, blk, 0, stream>>>(h_norm, wqt, qb, nullptr, nullptr, nullptr, NTOK, C_, C_);
  gemm_bt<0, 1><<<gQ, blk, 0, stream>>>(h_norm, wkt, kb, nullptr, nullptr, nullptr, NTOK, C_, C_);
  gemm_bt<0, 1><<<gQ, blk, 0, stream>>>(h_norm, wvt, vb, nullptr, nullptr, nullptr, NTOK, C_, C_);
  // attention
  attn_kernel<<<dim3(T_ / 64, B_ * H_), blk, 0, stream>>>(qb, kb, vb, fbuf);
  // f_total = force@w_o + b_o - 0.1*h_norm  (in-place over h_norm)
  gemm_bt<0, 2><<<gQ, blk, 0, stream>>>(fbuf, wot, h_norm, b_o, h_norm, nullptr, NTOK, C_, C_);
  // f_proj = f_total @ U
  gemm_bt<0, 0><<<(NTOK / 128) * (DI_ / 128), blk, 0, stream>>>(h_norm, ut, f_proj, nullptr,
                                                                nullptr, nullptr, NTOK, DI_, C_);
  // fsi + scan
  fsi_kernel<<<NTOK / 4, blk, 0, stream>>>(f_proj, hmagA, out_fsi);
  scan_kernel<<<B_, dim3(DI_), 0, stream>>>(f_proj, gammaA, coefA, out_m);
  // h_new = h + eps * (m @ V)
  gemm_bt<0, 3><<<gQ, blk, 0, stream>>>(out_m, vt, h_new, nullptr, h, epsA, NTOK, C_, DI_);
  // sys2 branch
  ln_kernel<0><<<NTOK, blk, 0, stream>>>(h_new, ln_w, ln_b, fbuf, nullptr, nullptr, nullptr,
                                         nullptr, nullptr, nullptr, nullptr, nullptr, nullptr,
                                         nullptr, nullptr);
  int gW = (NTOK / 128) * (C4 / 128);
  gemm_bt<0, 4><<<gW, blk, 0, stream>>>(fbuf, lg1t, act, lg_b1, nullptr, nullptr, NTOK, C4, C_);
  gemm_bt<1, 5><<<gQ, blk, 0, stream>>>(act, lg2t, h_pre, lg_b2, h_new, massA, NTOK, C_, C4);
  // mlp branch
  ln_kernel<0><<<NTOK, blk, 0, stream>>>(h_pre, ln_w, ln_b, fbuf, nullptr, nullptr, nullptr,
                                         nullptr, nullptr, nullptr, nullptr, nullptr, nullptr,
                                         nullptr, nullptr);
  gemm_bt<0, 4><<<gW, blk, 0, stream>>>(fbuf, mlp1t, act, mlp_b1, nullptr, nullptr, NTOK, C4, C_);
  gemm_bt<1, 6><<<gQ, blk, 0, stream>>>(act, mlp2t, out_h, mlp_b2, h_pre, nullptr, NTOK, C_, C4);
}

// Round 3
// 651.901 us; speedup vs baseline: 1.2700x; 1.2700x over previous
//
#include <hip/hip_runtime.h>
#include <hip/hip_bf16.h>
#include <math.h>

typedef __attribute__((ext_vector_type(8))) short bf16x8;
typedef __attribute__((ext_vector_type(4))) float f32x4;

#define DEVI __device__ __forceinline__

constexpr int B_ = 4, T_ = 1024, C_ = 1024, H_ = 16, HD_ = 64, DI_ = 128;
constexpr int NTOK = B_ * T_;      // 4096
constexpr int C4 = 4 * C_;         // 4096
constexpr int C3 = 3 * C_;         // 3072
constexpr float LAMBDA_CONF = 0.1f;

DEVI short f2bf(float f) {
  unsigned u = __builtin_bit_cast(unsigned, f);
  u += 0x7fffu + ((u >> 16) & 1u);   // RNE
  return (short)(u >> 16);
}
DEVI unsigned pk2(float a, float b) {
  return (unsigned)(unsigned short)f2bf(a) | ((unsigned)(unsigned short)f2bf(b) << 16);
}
DEVI float sigm(float x) { return 1.f / (1.f + __expf(-x)); }
DEVI float geluf(float x) { return 0.5f * x * (1.f + erff(x * 0.70710678118654752440f)); }

// direct-to-LDS 16B async copy: per-lane global addr, wave-uniform LDS base + lane*16
DEVI void gload16(const void* g, void* l) {
  __builtin_amdgcn_global_load_lds((const __attribute__((address_space(1))) unsigned*)g,
                                   (__attribute__((address_space(3))) unsigned*)l, 16, 0, 0);
}

// ---------------- weight transpose + f32->bf16 convert: W[K][N] -> Wt[N][K] ----------------
__global__ __launch_bounds__(256) void transpose_cvt(const float* __restrict__ W,
                                                     short* __restrict__ Wt, int K, int N) {
  __shared__ float s[32][33];
  int n0 = blockIdx.x * 32, k0 = blockIdx.y * 32;
  int tx = threadIdx.x & 31, ty = threadIdx.x >> 5;  // ty 0..7
#pragma unroll
  for (int i = 0; i < 4; i++)
    s[ty + i * 8][tx] = W[(size_t)(k0 + ty + i * 8) * N + n0 + tx];
  __syncthreads();
#pragma unroll
  for (int i = 0; i < 4; i++)
    Wt[(size_t)(n0 + ty + i * 8) * K + k0 + tx] = f2bf(s[tx][ty + i * 8]);
}

// ---------------- block reduce helper (256 threads) ----------------
DEVI float blk_red(float v, volatile float* sm) {
  int lane = threadIdx.x & 63, wv = threadIdx.x >> 6;
#pragma unroll
  for (int o = 32; o; o >>= 1) v += __shfl_down(v, o);
  __syncthreads();
  if (lane == 0) sm[wv] = v;
  __syncthreads();
  return sm[0] + sm[1] + sm[2] + sm[3];
}

// ---------------- LayerNorm -> bf16 (and optional f32 copy + per-token gates) ----------------
template <int FULL, int WF32>
__global__ __launch_bounds__(256) void ln_kernel(
    const float* __restrict__ X, const float* __restrict__ lnw, const float* __restrict__ lnb,
    float* __restrict__ Out, short* __restrict__ OutBf,
    const float* __restrict__ gw, const float* __restrict__ gb,
    const float* __restrict__ mw, const float* __restrict__ mb,
    const float* __restrict__ ew, const float* __restrict__ eb,
    float* __restrict__ gammaA, float* __restrict__ epsA, float* __restrict__ massA,
    float* __restrict__ coefA, float* __restrict__ hmagA) {
  __shared__ float sm[4];
  int tok = blockIdx.x;
  const float* x = X + (size_t)tok * C_;
  int t4 = threadIdx.x * 4;
  float4 xv = *(const float4*)&x[t4];
  float s = xv.x + xv.y + xv.z + xv.w;
  float ss = xv.x * xv.x + xv.y * xv.y + xv.z * xv.z + xv.w * xv.w;
  s = blk_red(s, sm);
  ss = blk_red(ss, sm);
  float mu = s * (1.f / C_);
  float var = ss * (1.f / C_) - mu * mu;
  float rs = rsqrtf(var + 1e-5f);
  float4 wv = *(const float4*)&lnw[t4];
  float4 bv = *(const float4*)&lnb[t4];
  float4 hn;
  hn.x = (xv.x - mu) * rs * wv.x + bv.x;
  hn.y = (xv.y - mu) * rs * wv.y + bv.y;
  hn.z = (xv.z - mu) * rs * wv.z + bv.z;
  hn.w = (xv.w - mu) * rs * wv.w + bv.w;
  if (WF32) *(float4*)&Out[(size_t)tok * C_ + t4] = hn;
  short4 ob;
  ob.x = f2bf(hn.x); ob.y = f2bf(hn.y); ob.z = f2bf(hn.z); ob.w = f2bf(hn.w);
  *(short4*)&OutBf[(size_t)tok * C_ + t4] = ob;
  if (FULL) {
    float4 gwv = *(const float4*)&gw[t4];
    float4 mwv = *(const float4*)&mw[t4];
    float4 ewv = *(const float4*)&ew[t4];
    float gd = hn.x * gwv.x + hn.y * gwv.y + hn.z * gwv.z + hn.w * gwv.w;
    float md = xv.x * mwv.x + xv.y * mwv.y + xv.z * mwv.z + xv.w * mwv.w;
    float ed = xv.x * ewv.x + xv.y * ewv.y + xv.z * ewv.z + xv.w * ewv.w;
    float h2 = hn.x * hn.x + hn.y * hn.y + hn.z * hn.z + hn.w * hn.w;
    gd = blk_red(gd, sm);
    md = blk_red(md, sm);
    ed = blk_red(ed, sm);
    h2 = blk_red(h2, sm);
    if (threadIdx.x == 0) {
      float g = sigm(gd + gb[0]);
      float xm = md + mb[0];
      float sp = (xm > 20.f) ? xm : log1pf(expf(xm));
      float msv = 1.f + sp;
      float epv = sigm(ed + eb[0]);
      gammaA[tok] = g;
      massA[tok] = msv;
      epsA[tok] = epv;
      coefA[tok] = epv / msv;
      hmagA[tok] = sqrtf(h2);
    }
  }
}

// ---------------- bf16 MFMA GEMM (m97 structure): C[M,N] = A[M,K] * Bt[N,K]^T ----------------
// 128x128 tile, BK=32, global_load_lds width=16 staging, linear LDS, 2 barriers/K-step.
// EPI: 0 f32, 1 bf16, 2 bf16(v+bias-0.1*resid_f32), 3 f32(resid + tokv[row]*v),
//      4 bf16 gelu(v+bias), 5 f32(resid + sigm(tokv[row]-1)*(v+bias)), 6 f32(resid+v+bias)
template <int EPI>
__global__ __launch_bounds__(256) void gemm_bt(
    const short* __restrict__ A, const short* __restrict__ Bt, void* __restrict__ Outp,
    const float* __restrict__ bias, const float* __restrict__ resid,
    const float* __restrict__ tokv, int M, int N, int K) {
  __shared__ short As[128][32];
  __shared__ short Bs[128][32];
  int tid = threadIdx.x, lane = tid & 63, w = tid >> 6;
  int wr = w >> 1, wc = w & 1;
  int fr = lane & 15, fg = lane >> 4;
  int nT = N >> 7;
  int bm = (blockIdx.x / nT) << 7;
  int bn = (blockIdx.x % nT) << 7;
  f32x4 acc[4][4] = {};
  int lr = lane >> 2;          // 0..15: row within a 16-row stripe
  int lc = (lane & 3) << 3;    // 0,8,16,24: bf16 col

  const short* ga0 = A + (size_t)(bm + w * 16 + lr) * K + lc;
  const short* ga1 = A + (size_t)(bm + 64 + w * 16 + lr) * K + lc;
  const short* gb0 = Bt + (size_t)(bn + w * 16 + lr) * K + lc;
  const short* gb1 = Bt + (size_t)(bn + 64 + w * 16 + lr) * K + lc;

  for (int kt = 0; kt < K; kt += 32) {
    gload16(ga0 + kt, &As[w * 16][0]);
    gload16(ga1 + kt, &As[64 + w * 16][0]);
    gload16(gb0 + kt, &Bs[w * 16][0]);
    gload16(gb1 + kt, &Bs[64 + w * 16][0]);
    __syncthreads();  // drains vmcnt before any lane reads LDS
    bf16x8 af[4], bfv[4];
#pragma unroll
    for (int i = 0; i < 4; i++) af[i] = *(const bf16x8*)&As[wr * 64 + i * 16 + fr][fg * 8];
#pragma unroll
    for (int i = 0; i < 4; i++) bfv[i] = *(const bf16x8*)&Bs[wc * 64 + i * 16 + fr][fg * 8];
#pragma unroll
    for (int mi = 0; mi < 4; mi++)
#pragma unroll
      for (int ni = 0; ni < 4; ni++)
        acc[mi][ni] = __builtin_amdgcn_mfma_f32_16x16x32_bf16(af[mi], bfv[ni], acc[mi][ni], 0, 0, 0);
    __syncthreads();
  }

#pragma unroll
  for (int mi = 0; mi < 4; mi++) {
    int row0 = bm + wr * 64 + mi * 16 + fg * 4;
#pragma unroll
    for (int ni = 0; ni < 4; ni++) {
      int col = bn + wc * 64 + ni * 16 + fr;
#pragma unroll
      for (int r = 0; r < 4; r++) {
        int row = row0 + r;
        size_t idx = (size_t)row * N + col;
        float v = acc[mi][ni][r];
        if (EPI == 0) {
          ((float*)Outp)[idx] = v;
        } else if (EPI == 1) {
          ((short*)Outp)[idx] = f2bf(v);
        } else if (EPI == 2) {
          ((short*)Outp)[idx] = f2bf(v + bias[col] - LAMBDA_CONF * resid[idx]);
        } else if (EPI == 3) {
          ((float*)Outp)[idx] = resid[idx] + tokv[row] * v;
        } else if (EPI == 4) {
          float x = v + bias[col];
          ((short*)Outp)[idx] = f2bf(geluf(x));
        } else if (EPI == 5) {
          float x = v + bias[col];
          float g = sigm(tokv[row] - 1.f);
          ((float*)Outp)[idx] = resid[idx] + g * x;
        } else if (EPI == 6) {
          ((float*)Outp)[idx] = resid[idx] + v + bias[col];
        }
      }
    }
  }
}

// ---------------- flash attention (full, non-causal), bf16 MFMA ----------------
// QKV interleaved [tok][3C]; grid (T/64, B*H); 4 waves, 16 q-rows each; out bf16
__global__ __launch_bounds__(256) void attn_kernel(const short* __restrict__ QKV,
                                                   short* __restrict__ Fout) {
  __shared__ short Ks[32][72];
  __shared__ short Vs[64][40];
  __shared__ short Ps[4][16][32];
  int bh = blockIdx.y;
  int b = bh >> 4, h = bh & 15;
  int qt0 = blockIdx.x * 64;
  int tid = threadIdx.x, lane = tid & 63, w = tid >> 6;
  int fr = lane & 15, fg = lane >> 4;

  size_t base = ((size_t)b * T_) * C3 + h * 64;
  const short* Qp = QKV + base;
  const short* Kp = QKV + base + C_;
  const short* Vp = QKV + base + 2 * C_;
  int qrow = qt0 + w * 16 + fr;
  bf16x8 qf0 = *(const bf16x8*)&Qp[(size_t)qrow * C3 + fg * 8];
  bf16x8 qf1 = *(const bf16x8*)&Qp[(size_t)qrow * C3 + 32 + fg * 8];

  f32x4 oacc[4] = {};
  float m_run = -1e30f, l_run = 0.f;

  int srow = tid >> 3;
  int scol = (tid & 7) * 8;

  for (int kt = 0; kt < T_; kt += 32) {
    *(uint4*)&Ks[srow][scol] = *(const uint4*)&Kp[(size_t)(kt + srow) * C3 + scol];
    {
      uint4 vv = *(const uint4*)&Vp[(size_t)(kt + srow) * C3 + scol];
      const short* sp = (const short*)&vv;
#pragma unroll
      for (int i = 0; i < 8; i++) Vs[scol + i][srow] = sp[i];
    }
    __syncthreads();

    // S^T = K * Q^T  (rows = keys, cols = q-rows)
    f32x4 sacc[2];
#pragma unroll
    for (int kb = 0; kb < 2; kb++) {
      f32x4 z = {};
      bf16x8 kf0 = *(const bf16x8*)&Ks[kb * 16 + fr][fg * 8];
      bf16x8 kf1 = *(const bf16x8*)&Ks[kb * 16 + fr][32 + fg * 8];
      z = __builtin_amdgcn_mfma_f32_16x16x32_bf16(kf0, qf0, z, 0, 0, 0);
      z = __builtin_amdgcn_mfma_f32_16x16x32_bf16(kf1, qf1, z, 0, 0, 0);
      sacc[kb] = z;
    }
    float mt = -1e30f;
#pragma unroll
    for (int kb = 0; kb < 2; kb++)
#pragma unroll
      for (int r = 0; r < 4; r++) {
        sacc[kb][r] *= 0.125f;  // 1/sqrt(64)/TAU
        mt = fmaxf(mt, sacc[kb][r]);
      }
    mt = fmaxf(mt, __shfl_xor(mt, 16));
    mt = fmaxf(mt, __shfl_xor(mt, 32));
    float m_new = fmaxf(m_run, mt);
    float alpha = __expf(m_run - m_new);
    float psum = 0.f;
    float pv[8];
#pragma unroll
    for (int kb = 0; kb < 2; kb++)
#pragma unroll
      for (int r = 0; r < 4; r++) {
        float p = __expf(sacc[kb][r] - m_new);
        pv[kb * 4 + r] = p;
        psum += p;
      }
    psum += __shfl_xor(psum, 16);
    psum += __shfl_xor(psum, 32);
    l_run = l_run * alpha + psum;
    m_run = m_new;

    {
      uint2 p0, p1;
      p0.x = pk2(pv[0], pv[1]); p0.y = pk2(pv[2], pv[3]);
      p1.x = pk2(pv[4], pv[5]); p1.y = pk2(pv[6], pv[7]);
      *(uint2*)&Ps[w][fr][fg * 4] = p0;
      *(uint2*)&Ps[w][fr][16 + fg * 4] = p1;
    }
    float ar[4];
#pragma unroll
    for (int r = 0; r < 4; r++) ar[r] = __shfl(alpha, fg * 4 + r);
#pragma unroll
    for (int ni = 0; ni < 4; ni++)
#pragma unroll
      for (int r = 0; r < 4; r++) oacc[ni][r] *= ar[r];

    asm volatile("s_waitcnt lgkmcnt(0)" ::: "memory");
    bf16x8 pa = *(const bf16x8*)&Ps[w][fr][fg * 8];
#pragma unroll
    for (int ni = 0; ni < 4; ni++) {
      bf16x8 vf = *(const bf16x8*)&Vs[ni * 16 + fr][fg * 8];
      oacc[ni] = __builtin_amdgcn_mfma_f32_16x16x32_bf16(pa, vf, oacc[ni], 0, 0, 0);
    }
    __syncthreads();
  }

  float lr4[4];
#pragma unroll
  for (int r = 0; r < 4; r++) lr4[r] = __shfl(l_run, fg * 4 + r);
#pragma unroll
  for (int ni = 0; ni < 4; ni++)
#pragma unroll
    for (int r = 0; r < 4; r++) {
      int tok = b * T_ + qt0 + w * 16 + fg * 4 + r;
      Fout[(size_t)tok * C_ + h * 64 + ni * 16 + fr] = f2bf(oacc[ni][r] / lr4[r]);
    }
}

// ---------------- sequential momentum scan: m_t = g_t*m + c_t*f_t ----------------
__global__ __launch_bounds__(128) void scan_kernel(const float* __restrict__ f_proj,
                                                   const float* __restrict__ gam,
                                                   const float* __restrict__ coef,
                                                   float* __restrict__ m_out,
                                                   short* __restrict__ m_bf) {
  int b = blockIdx.x;
  int d = threadIdx.x;
  const float* fp = f_proj + (size_t)b * T_ * DI_ + d;
  const float* g = gam + (size_t)b * T_;
  const float* c = coef + (size_t)b * T_;
  float* mo = m_out + (size_t)b * T_ * DI_ + d;
  short* mb = m_bf + (size_t)b * T_ * DI_ + d;
  float m = 0.f;
  for (int t = 0; t < T_; t += 8) {
    float fv[8], gv[8], cv[8];
#pragma unroll
    for (int i = 0; i < 8; i++) {
      fv[i] = fp[(size_t)(t + i) * DI_];
      gv[i] = g[t + i];
      cv[i] = c[t + i];
    }
#pragma unroll
    for (int i = 0; i < 8; i++) {
      m = gv[i] * m + cv[i] * fv[i];
      mo[(size_t)(t + i) * DI_] = m;
      mb[(size_t)(t + i) * DI_] = f2bf(m);
    }
  }
}

// ---------------- fsi ----------------
__global__ __launch_bounds__(256) void fsi_kernel(const float* __restrict__ f_proj,
                                                  const float* __restrict__ hmag,
                                                  float* __restrict__ fsi_out) {
  int tok = blockIdx.x * 4 + (threadIdx.x >> 6);
  int l = threadIdx.x & 63;
  float2 v = *(const float2*)&f_proj[(size_t)tok * DI_ + l * 2];
  float s = v.x * v.x + v.y * v.y;
#pragma unroll
  for (int o = 32; o; o >>= 1) s += __shfl_down(s, o);
  if (l == 0) fsi_out[tok] = hmag[tok] / (2.f * sqrtf(s) + 1e-6f);
}

// ---------------- launcher ----------------
extern "C" void kernel_launch(void* const* d_in, const int* in_sizes, int n_in,
                              void* d_out, int out_size, void* d_ws, size_t ws_size,
                              hipStream_t stream) {
  (void)in_sizes; (void)n_in; (void)out_size; (void)ws_size;
  const float* h = (const float*)d_in[0];
  const float* ln_w = (const float*)d_in[1];
  const float* ln_b = (const float*)d_in[2];
  const float* w_q = (const float*)d_in[3];
  const float* w_k = (const float*)d_in[4];
  const float* w_v = (const float*)d_in[5];
  const float* w_o = (const float*)d_in[6];
  const float* b_o = (const float*)d_in[7];
  const float* U = (const float*)d_in[8];
  const float* V = (const float*)d_in[9];
  const float* gamma_w = (const float*)d_in[10];
  const float* gamma_b = (const float*)d_in[11];
  const float* mass_w = (const float*)d_in[12];
  const float* mass_b = (const float*)d_in[13];
  const float* eps_w = (const float*)d_in[14];
  const float* eps_b = (const float*)d_in[15];
  const float* lg_w1 = (const float*)d_in[16];
  const float* lg_b1 = (const float*)d_in[17];
  const float* lg_w2 = (const float*)d_in[18];
  const float* lg_b2 = (const float*)d_in[19];
  const float* mlp_w1 = (const float*)d_in[20];
  const float* mlp_b1 = (const float*)d_in[21];
  const float* mlp_w2 = (const float*)d_in[22];
  const float* mlp_b2 = (const float*)d_in[23];

  float* out_h = (float*)d_out;
  float* out_m = out_h + (size_t)NTOK * C_;
  float* out_fsi = out_m + (size_t)NTOK * DI_;

  char* wsb = (char*)d_ws;
  size_t off = 0;
  auto al = [&](size_t bytes) {
    void* p = wsb + off;
    off += (bytes + 255) & ~(size_t)255;
    return p;
  };
  short* wqkvt = (short*)al((size_t)C3 * C_ * 2);          // [3C][C] concat q,k,v
  short* wot = (short*)al((size_t)C_ * C_ * 2);
  short* ut = (short*)al((size_t)DI_ * C_ * 2);
  short* vt = (short*)al((size_t)C_ * DI_ * 2);
  short* lg1t = (short*)al((size_t)C4 * C_ * 2);
  short* lg2t = (short*)al((size_t)C_ * C4 * 2);
  short* mlp1t = (short*)al((size_t)C4 * C_ * 2);
  short* mlp2t = (short*)al((size_t)C_ * C4 * 2);
  float* h_norm = (float*)al((size_t)NTOK * C_ * 4);       // f32 (resid for EPI2)
  short* hn_bf = (short*)al((size_t)NTOK * C_ * 2);        // bf16 h_norm, later f_total
  short* qkv_bf = (short*)al((size_t)NTOK * C3 * 2);       // Q|K|V interleaved; later h_new
  short* tmp_bf = (short*)al((size_t)NTOK * C_ * 2);       // force, hn2, hn3
  float* f_proj = (float*)al((size_t)NTOK * DI_ * 4);
  short* act = (short*)al((size_t)NTOK * C4 * 2);          // head also holds m_bf briefly
  float* h_pre = (float*)al((size_t)NTOK * C_ * 4);
  float* gammaA = (float*)al((size_t)NTOK * 4);
  float* epsA = (float*)al((size_t)NTOK * 4);
  float* massA = (float*)al((size_t)NTOK * 4);
  float* coefA = (float*)al((size_t)NTOK * 4);
  float* hmagA = (float*)al((size_t)NTOK * 4);
  short* ftot_bf = hn_bf;                                  // overlay (hn_bf free after QKV)
  short* m_bf = act;                                       // overlay (read before lg1 writes act)
  float* h_new = (float*)qkv_bf;                           // overlay (free after attention)

  dim3 blk(256);
  // weight prep
  transpose_cvt<<<dim3(C_ / 32, C_ / 32), blk, 0, stream>>>(w_q, wqkvt, C_, C_);
  transpose_cvt<<<dim3(C_ / 32, C_ / 32), blk, 0, stream>>>(w_k, wqkvt + (size_t)C_ * C_, C_, C_);
  transpose_cvt<<<dim3(C_ / 32, C_ / 32), blk, 0, stream>>>(w_v, wqkvt + (size_t)2 * C_ * C_, C_, C_);
  transpose_cvt<<<dim3(C_ / 32, C_ / 32), blk, 0, stream>>>(w_o, wot, C_, C_);
  transpose_cvt<<<dim3(DI_ / 32, C_ / 32), blk, 0, stream>>>(U, ut, C_, DI_);
  transpose_cvt<<<dim3(C_ / 32, DI_ / 32), blk, 0, stream>>>(V, vt, DI_, C_);
  transpose_cvt<<<dim3(C4 / 32, C_ / 32), blk, 0, stream>>>(lg_w1, lg1t, C_, C4);
  transpose_cvt<<<dim3(C_ / 32, C4 / 32), blk, 0, stream>>>(lg_w2, lg2t, C4, C_);
  transpose_cvt<<<dim3(C4 / 32, C_ / 32), blk, 0, stream>>>(mlp_w1, mlp1t, C_, C4);
  transpose_cvt<<<dim3(C_ / 32, C4 / 32), blk, 0, stream>>>(mlp_w2, mlp2t, C4, C_);

  // LN1 + gates (writes f32 + bf16)
  ln_kernel<1, 1><<<NTOK, blk, 0, stream>>>(h, ln_w, ln_b, h_norm, hn_bf, gamma_w, gamma_b,
                                            mass_w, mass_b, eps_w, eps_b, gammaA, epsA, massA,
                                            coefA, hmagA);
  // fused QKV: [4096,3072,1024]
  gemm_bt<1><<<(NTOK / 128) * (C3 / 128), blk, 0, stream>>>(hn_bf, wqkvt, qkv_bf, nullptr,
                                                            nullptr, nullptr, NTOK, C3, C_);
  // attention -> force (bf16)
  attn_kernel<<<dim3(T_ / 64, B_ * H_), blk, 0, stream>>>(qkv_bf, tmp_bf);
  int gQ = (NTOK / 128) * (C_ / 128);
  // f_total = force@w_o + b_o - 0.1*h_norm  -> bf16
  gemm_bt<2><<<gQ, blk, 0, stream>>>(tmp_bf, wot, ftot_bf, b_o, h_norm, nullptr, NTOK, C_, C_);
  // f_proj = f_total @ U
  gemm_bt<0><<<(NTOK / 128) * (DI_ / 128), blk, 0, stream>>>(ftot_bf, ut, f_proj, nullptr,
                                                             nullptr, nullptr, NTOK, DI_, C_);
  // fsi + scan
  fsi_kernel<<<NTOK / 4, blk, 0, stream>>>(f_proj, hmagA, out_fsi);
  scan_kernel<<<B_, dim3(DI_), 0, stream>>>(f_proj, gammaA, coefA, out_m, m_bf);
  // h_new = h + eps * (m @ V)
  gemm_bt<3><<<gQ, blk, 0, stream>>>(m_bf, vt, h_new, nullptr, h, epsA, NTOK, C_, DI_);
  // sys2 branch
  ln_kernel<0, 0><<<NTOK, blk, 0, stream>>>(h_new, ln_w, ln_b, nullptr, tmp_bf, nullptr, nullptr,
                                            nullptr, nullptr, nullptr, nullptr, nullptr, nullptr,
                                            nullptr, nullptr, nullptr);
  int gW = (NTOK / 128) * (C4 / 128);
  gemm_bt<4><<<gW, blk, 0, stream>>>(tmp_bf, lg1t, act, lg_b1, nullptr, nullptr, NTOK, C4, C_);
  gemm_bt<5><<<gQ, blk, 0, stream>>>(act, lg2t, h_pre, lg_b2, h_new, massA, NTOK, C_, C4);
  // mlp branch
  ln_kernel<0, 0><<<NTOK, blk, 0, stream>>>(h_pre, ln_w, ln_b, nullptr, tmp_bf, nullptr, nullptr,
                                            nullptr, nullptr, nullptr, nullptr, nullptr, nullptr,
                                            nullptr, nullptr, nullptr);
  gemm_bt<4><<<gW, blk, 0, stream>>>(tmp_bf, mlp1t, act, mlp_b1, nullptr, nullptr, NTOK, C4, C_);
  gemm_bt<6><<<gQ, blk, 0, stream>>>(act, mlp2t, out_h, mlp_b2, h_pre, nullptr, NTOK, C_, C4);
}